// Round 9
// baseline (95.906 us; speedup 1.0000x reference)
//
#include <hip/hip_runtime.h>

#define BDIM 128
#define TDIM 512
#define DDIM 64
#define HDIM 256
#define BH   (BDIM * HDIM)             // 32768

// sbuf float-offset map
#define PLN_OFF 0                      // 4 planes x BH
#define W_OFF   (4 * BH)               // per-b {W0,W1}: 256 floats
#define HH_OFF  (W_OFF + 256)          // B x 1024
#define W01_OFF (HH_OFF + BDIM * 1024) // B x T float2 (131072 floats)
#define XBF_OFF (W01_OFF + BDIM * TDIM * 2)  // bf16 x, as shorts from here

// pre-kernel block-role ranges (512 threads each)
#define NCONV 1024                     // x->bf16: 1024 blocks x 4096 floats
#define NHH   256                      // hh: 128 b x 2 halves
#define NW01  128                      // w01 + W sums: 1 block per b
#define NPRE  (NCONV + NHH + NW01)

typedef short s16x8 __attribute__((ext_vector_type(8)));
typedef float f32x4 __attribute__((ext_vector_type(4)));

#if __has_builtin(__builtin_amdgcn_exp2f)
#define EXP2(x) __builtin_amdgcn_exp2f(x)
#else
#define EXP2(x) exp2f(x)
#endif
#define L2E 1.44269504f

__device__ __forceinline__ float rcpf(float x) { return __builtin_amdgcn_rcpf(x); }

__device__ __forceinline__ short f2bf(float f) {
  __bf16 b = (__bf16)f;
  return __builtin_bit_cast(short, b);
}

__device__ __forceinline__ s16x8 pack_bf8(float4 lo, float4 hi) {
  s16x8 v;
  v[0] = f2bf(lo.x); v[1] = f2bf(lo.y); v[2] = f2bf(lo.z); v[3] = f2bf(lo.w);
  v[4] = f2bf(hi.x); v[5] = f2bf(hi.y); v[6] = f2bf(hi.z); v[7] = f2bf(hi.w);
  return v;
}

__device__ __forceinline__ s16x8 pack_bf8s(float4 lo, float4 hi, float s) {
  s16x8 v;
  v[0] = f2bf(lo.x*s); v[1] = f2bf(lo.y*s); v[2] = f2bf(lo.z*s); v[3] = f2bf(lo.w*s);
  v[4] = f2bf(hi.x*s); v[5] = f2bf(hi.y*s); v[6] = f2bf(hi.z*s); v[7] = f2bf(hi.w*s);
  return v;
}

// Union prologue: blocks [0,NCONV) convert x->bf16; [NCONV,NCONV+NHH) compute
// hh = Whh.h0 + biases; [.., +NW01) build compact w01[b][t] + per-b W0/W1.
__global__ __launch_bounds__(512) void pre_kernel(
    const float* __restrict__ x, const float* __restrict__ h0,
    const float* __restrict__ Whh, const float* __restrict__ bih,
    const float* __restrict__ bhh, const int* __restrict__ longp,
    float* __restrict__ sbuf)
{
  const int blk = blockIdx.x, tid = threadIdx.x;
  __shared__ float h0s[HDIM];
  __shared__ float rsum[16];

  if (blk < NCONV) {
    // ---- x -> bf16 (layout preserved) ----
    short* xbfs = (short*)(sbuf + XBF_OFF);
    const size_t i0 = (size_t)blk * 4096 + (size_t)tid * 8;
    float4 lo = *(const float4*)(x + i0);
    float4 hi = *(const float4*)(x + i0 + 4);
    *(s16x8*)(xbfs + i0) = pack_bf8(lo, hi);
  } else if (blk < NCONV + NHH) {
    // ---- hh[b][colw] = Whh[colw].h0[b] + bih + bhh ----
    const int hb = blk - NCONV;
    const int b = hb >> 1, half = hb & 1;
    if (tid < HDIM) h0s[tid] = h0[b * HDIM + tid];
    __syncthreads();
    const int colw = half * 512 + tid;
    const float4* wr = (const float4*)(Whh + (size_t)colw * HDIM);
    const float4* hv = (const float4*)h0s;
    float acc = 0.f;
    #pragma unroll 8
    for (int k = 0; k < HDIM / 4; ++k) {
      float4 w = wr[k], h4 = hv[k];
      acc += w.x * h4.x + w.y * h4.y + w.z * h4.z + w.w * h4.w;
    }
    sbuf[HH_OFF + (size_t)b * 1024 + colw] = acc + bih[colw] + bhh[colw];
  } else {
    // ---- compact w01[b][t] (t=0 zeroed, /long folded) + W0/W1 full sums ----
    const int b = blk - (NCONV + NHH);
    const float inv_long = 1.0f / (float)(*longp);
    const float2 v = *(const float2*)(x + ((size_t)b * TDIM + tid) * DDIM);
    float2* w01p = (float2*)(sbuf + W01_OFF);
    w01p[(size_t)b * TDIM + tid] =
        (tid == 0) ? make_float2(0.f, 0.f) : make_float2(v.x * inv_long, v.y);
    // full-t sums (include t=0)
    float sa = v.x, sb = v.y;
    #pragma unroll
    for (int off = 1; off < 64; off <<= 1) {
      sa += __shfl_xor(sa, off, 64);
      sb += __shfl_xor(sb, off, 64);
    }
    const int wave = tid >> 6, lane = tid & 63;
    if (lane == 0) { rsum[wave] = sa; rsum[8 + wave] = sb; }
    __syncthreads();
    if (tid == 0) {
      float Sa = 0.f, Sb = 0.f;
      #pragma unroll
      for (int w = 0; w < 8; ++w) { Sa += rsum[w]; Sb += rsum[8 + w]; }
      sbuf[W_OFF + b * 2 + 0] = Sa * inv_long;
      sbuf[W_OFF + b * 2 + 1] = Sb;
    }
  }
}

// Grid: (128, 8), 512 threads = 8 waves, zero in-loop barriers.
// Wave = (tq = wave>>1: 128-t quarter, hp = wave&1: 16-h slice).
// A-fragments load DIRECTLY as bf16 s16x8 (2 loads/iter, no pack VALU).
// w0/w1 from 4KB coalesced-staged LDS (float2, banks {0,8,16,24} per read).
// 2-slot software pipeline covers L2 latency.
__global__ __launch_bounds__(512, 4) void fused_lstm(
    const float* __restrict__ c0, const float* __restrict__ Wih,
    float* __restrict__ sbuf)
{
  const int b    = blockIdx.x;
  const int hcq  = blockIdx.y;          // 0..7
  const int tid  = threadIdx.x;
  const int wave = tid >> 6;            // 0..7
  const int lane = tid & 63;
  const int col  = lane & 15;
  const int kg   = lane >> 4;           // 0..3
  const int hp   = wave & 1;
  const int tq   = wave >> 1;           // 0..3
  const int hc   = hcq * 2 + hp;        // 0..15
  const int h    = hc * 16 + col;

  __shared__ float2 ws01[TDIM];         // 4KB
  __shared__ float red[8 * 64];         // 2KB

  const float* hh = sbuf + HH_OFF;
  const float2* w01p = (const float2*)(sbuf + W01_OFF);
  const short* xbfs = (const short*)(sbuf + XBF_OFF);

  ws01[tid] = w01p[(size_t)b * TDIM + tid];   // coalesced 4KB stage
  __syncthreads();

  const float SC[4] = {L2E, L2E, 2.f * L2E, L2E};
  float hhv[4];
  #pragma unroll
  for (int g = 0; g < 4; ++g)
    hhv[g] = hh[(size_t)b * 1024 + g * HDIM + h] * SC[g];
  const float cprev = c0[b * HDIM + h];

  // W_ih fragments (B operand), pre-scaled by SC[g]
  s16x8 wf[4][2];
  #pragma unroll
  for (int g = 0; g < 4; ++g) {
    const float4* wrow = (const float4*)(Wih + (size_t)(g * HDIM + h) * DDIM);
    #pragma unroll
    for (int ks = 0; ks < 2; ++ks)
      wf[g][ks] = pack_bf8s(wrow[kg * 2 + ks * 8], wrow[kg * 2 + ks * 8 + 1], SC[g]);
  }

  // A rows: bf16 row stride 64 shorts; lane reads 16B at kg*8 (+32 for k+32)
  const int t0w = tq * 128;
  const short* xr = xbfs + ((size_t)b * TDIM + t0w + col) * DDIM + kg * 8;

  s16x8 A0a, A1a, A0b, A1b;
  #define LOADT(i, V0, V1) { const short* p = xr + (size_t)(i) * 16 * DDIM; \
      V0 = *(const s16x8*)p; V1 = *(const s16x8*)(p + 32); }

  float s0h = 0.f, s1h = 0.f, s0c = 0.f, s1c = 0.f;

  #define COMPUTE(i, V0, V1) {                                               \
    f32x4 acc[4];                                                            \
    _Pragma("unroll")                                                        \
    for (int g = 0; g < 4; ++g) {                                            \
      f32x4 zc = {hhv[g], hhv[g], hhv[g], hhv[g]};                           \
      zc = __builtin_amdgcn_mfma_f32_16x16x32_bf16(V0, wf[g][0], zc, 0,0,0); \
      zc = __builtin_amdgcn_mfma_f32_16x16x32_bf16(V1, wf[g][1], zc, 0,0,0); \
      acc[g] = zc;                                                           \
    }                                                                        \
    _Pragma("unroll")                                                        \
    for (int r = 0; r < 4; ++r) {                                            \
      float2 wv = ws01[t0w + (i) * 16 + kg * 4 + r];                         \
      float ig = rcpf(1.f + EXP2(-acc[0][r]));                               \
      float fg = rcpf(1.f + EXP2(-acc[1][r]));                               \
      float gg = fmaf(-2.f, rcpf(EXP2(acc[2][r]) + 1.f), 1.f);               \
      float og = rcpf(1.f + EXP2(-acc[3][r]));                               \
      float cc = fmaf(fg, cprev, ig * gg);                                   \
      float th = fmaf(-2.f, rcpf(EXP2(cc * (2.f * L2E)) + 1.f), 1.f);        \
      float hv = og * th;                                                    \
      s0h = fmaf(hv, wv.x, s0h); s1h = fmaf(hv, wv.y, s1h);                  \
      s0c = fmaf(cc, wv.x, s0c); s1c = fmaf(cc, wv.y, s1c);                  \
    } }

  LOADT(0, A0a, A1a);
  LOADT(1, A0b, A1b);
  COMPUTE(0, A0a, A1a); LOADT(2, A0a, A1a);
  COMPUTE(1, A0b, A1b); LOADT(3, A0b, A1b);
  COMPUTE(2, A0a, A1a); LOADT(4, A0a, A1a);
  COMPUTE(3, A0b, A1b); LOADT(5, A0b, A1b);
  COMPUTE(4, A0a, A1a); LOADT(6, A0a, A1a);
  COMPUTE(5, A0b, A1b); LOADT(7, A0b, A1b);
  COMPUTE(6, A0a, A1a);
  COMPUTE(7, A0b, A1b);

  // reduce over the 4 k-groups (lanes sharing col)
  s0h += __shfl_xor(s0h, 16, 64); s0h += __shfl_xor(s0h, 32, 64);
  s1h += __shfl_xor(s1h, 16, 64); s1h += __shfl_xor(s1h, 32, 64);
  s0c += __shfl_xor(s0c, 16, 64); s0c += __shfl_xor(s0c, 32, 64);
  s1c += __shfl_xor(s1c, 16, 64); s1c += __shfl_xor(s1c, 32, 64);

  if (kg == 0) {
    red[wave * 64 +  0 + col] = s0h;    // w01 already carries /long + t=0 mask
    red[wave * 64 + 16 + col] = s1h;
    red[wave * 64 + 32 + col] = s0c;
    red[wave * 64 + 48 + col] = s1c;
  }
  __syncthreads();

  if (tid < 128) {
    const int hp2 = tid >> 6;
    const int q   = (tid >> 4) & 3;
    const int c   = tid & 15;
    const int o   = q * 16 + c;
    float s = red[(0 + hp2) * 64 + o] + red[(2 + hp2) * 64 + o] +
              red[(4 + hp2) * 64 + o] + red[(6 + hp2) * 64 + o];
    const int h2 = (hcq * 2 + hp2) * 16 + c;
    sbuf[(size_t)q * BH + b * HDIM + h2] = s;
  }
}

// Grid: 128 blocks (b), 256 threads. Pure GEMV epilogue.
__global__ __launch_bounds__(256) void out_kernel(
    const float* __restrict__ f1w, const float* __restrict__ f1b,
    const float* __restrict__ f2w, const float* __restrict__ f2b,
    const float* __restrict__ sbuf, float* __restrict__ out)
{
  const int b = blockIdx.x, tid = threadIdx.x;
  __shared__ float s0h[256], s1h[256], s0c[256], s1c[256];

  s0h[tid] = sbuf[(size_t)0 * BH + b * HDIM + tid];
  s1h[tid] = sbuf[(size_t)1 * BH + b * HDIM + tid];
  s0c[tid] = sbuf[(size_t)2 * BH + b * HDIM + tid];
  s1c[tid] = sbuf[(size_t)3 * BH + b * HDIM + tid];
  __syncthreads();

  const float W0 = sbuf[W_OFF + b * 2 + 0];
  const float W1 = sbuf[W_OFF + b * 2 + 1];

  float rh, rc;
  if (tid < 128) {                       // "first": f1_w with w0-weighted sums
    const float4* wr = (const float4*)(f1w + (size_t)tid * HDIM);
    float ah = 0.f, ac = 0.f;
    #pragma unroll 8
    for (int k = 0; k < HDIM / 4; ++k) {
      float4 w = wr[k];
      ah += w.x * s0h[4*k] + w.y * s0h[4*k+1] + w.z * s0h[4*k+2] + w.w * s0h[4*k+3];
      ac += w.x * s0c[4*k] + w.y * s0c[4*k+1] + w.z * s0c[4*k+2] + w.w * s0c[4*k+3];
    }
    const float bb = f1b[tid];
    rh = ah + bb * W0;
    rc = ac + bb * W0;
  } else {                               // "second": f2_w with w1-weighted sums
    const int k0 = tid - 128;
    const float4* wr = (const float4*)(f2w + (size_t)k0 * HDIM);
    float ah = 0.f, ac = 0.f;
    #pragma unroll 8
    for (int k = 0; k < HDIM / 4; ++k) {
      float4 w = wr[k];
      ah += w.x * s1h[4*k] + w.y * s1h[4*k+1] + w.z * s1h[4*k+2] + w.w * s1h[4*k+3];
      ac += w.x * s1c[4*k] + w.y * s1c[4*k+1] + w.z * s1c[4*k+2] + w.w * s1c[4*k+3];
    }
    const float bb = f2b[k0];
    rh = ah + bb * W1;
    rc = ac + bb * W1;
  }
  out[b * HDIM + tid] = rh;                      // agg(h_all) -> (1,B,256)
  out[BDIM * HDIM + b * HDIM + tid] = rc;        // agg(c_all)
}

extern "C" void kernel_launch(void* const* d_in, const int* in_sizes, int n_in,
                              void* d_out, int out_size, void* d_ws, size_t ws_size,
                              hipStream_t stream) {
  const float* x   = (const float*)d_in[0];
  const float* h0  = (const float*)d_in[1];
  const float* c0  = (const float*)d_in[2];
  const float* Wih = (const float*)d_in[3];
  const float* Whh = (const float*)d_in[4];
  const float* bih = (const float*)d_in[5];
  const float* bhh = (const float*)d_in[6];
  const float* f1w = (const float*)d_in[7];
  const float* f1b = (const float*)d_in[8];
  const float* f2w = (const float*)d_in[9];
  const float* f2b = (const float*)d_in[10];
  const int*  longp = (const int*)d_in[11];
  float* out  = (float*)d_out;
  float* sbuf = (float*)d_ws;   // ~10 MB: planes+W+hh+w01+xbf

  pre_kernel<<<NPRE, 512, 0, stream>>>(x, h0, Whh, bih, bhh, longp, sbuf);
  dim3 g1(BDIM, 8);
  fused_lstm<<<g1, 512, 0, stream>>>(c0, Wih, sbuf);
  out_kernel<<<BDIM, 256, 0, stream>>>(f1w, f1b, f2w, f2b, sbuf, out);
}

// Round 10
// 68.912 us; speedup vs baseline: 1.3917x; 1.3917x over previous
//
#include <hip/hip_runtime.h>

#define BDIM 128
#define TDIM 512
#define DDIM 64
#define HDIM 256
#define BH   (BDIM * HDIM)             // 32768

// sbuf float-offset map
#define PLN_OFF 0                      // 4 planes x BH
#define W_OFF   (4 * BH)               // per-b {W0,W1}: 256 floats
#define W01_OFF (W_OFF + 256)          // B x T float2 (131072 floats)
#define XBF_OFF (W01_OFF + BDIM * TDIM * 2)  // bf16 x, as shorts from here

// pre-kernel block-role ranges (512 threads each)
#define NCONV 1024                     // x->bf16: 1024 blocks x 4096 floats
#define NW01  128                      // w01 + W sums: 1 block per b
#define NPRE  (NCONV + NW01)

typedef short s16x8 __attribute__((ext_vector_type(8)));
typedef float f32x4 __attribute__((ext_vector_type(4)));

#if __has_builtin(__builtin_amdgcn_exp2f)
#define EXP2(x) __builtin_amdgcn_exp2f(x)
#else
#define EXP2(x) exp2f(x)
#endif
#define L2E 1.44269504f

__device__ __forceinline__ float rcpf(float x) { return __builtin_amdgcn_rcpf(x); }

__device__ __forceinline__ short f2bf(float f) {
  __bf16 b = (__bf16)f;
  return __builtin_bit_cast(short, b);
}

__device__ __forceinline__ s16x8 pack_bf8(float4 lo, float4 hi) {
  s16x8 v;
  v[0] = f2bf(lo.x); v[1] = f2bf(lo.y); v[2] = f2bf(lo.z); v[3] = f2bf(lo.w);
  v[4] = f2bf(hi.x); v[5] = f2bf(hi.y); v[6] = f2bf(hi.z); v[7] = f2bf(hi.w);
  return v;
}

__device__ __forceinline__ s16x8 pack_bf8s(float4 lo, float4 hi, float s) {
  s16x8 v;
  v[0] = f2bf(lo.x*s); v[1] = f2bf(lo.y*s); v[2] = f2bf(lo.z*s); v[3] = f2bf(lo.w*s);
  v[4] = f2bf(hi.x*s); v[5] = f2bf(hi.y*s); v[6] = f2bf(hi.z*s); v[7] = f2bf(hi.w*s);
  return v;
}

// Streaming-only prologue: blocks [0,NCONV) convert x->bf16 (coalesced);
// [NCONV, +NW01) build compact w01[b][t] + per-b W0/W1 sums.
// (hh moved INTO fused_lstm: its scattered GEMV was the hidden ~20-60us sink
//  as a standalone/tail kernel across R4-R9.)
__global__ __launch_bounds__(512) void pre_kernel(
    const float* __restrict__ x, const int* __restrict__ longp,
    float* __restrict__ sbuf)
{
  const int blk = blockIdx.x, tid = threadIdx.x;
  __shared__ float rsum[16];

  if (blk < NCONV) {
    // ---- x -> bf16 (layout preserved) ----
    short* xbfs = (short*)(sbuf + XBF_OFF);
    const size_t i0 = (size_t)blk * 4096 + (size_t)tid * 8;
    float4 lo = *(const float4*)(x + i0);
    float4 hi = *(const float4*)(x + i0 + 4);
    *(s16x8*)(xbfs + i0) = pack_bf8(lo, hi);
  } else {
    // ---- compact w01[b][t] (t=0 zeroed, /long folded) + W0/W1 full sums ----
    const int b = blk - NCONV;
    const float inv_long = 1.0f / (float)(*longp);
    const float2 v = *(const float2*)(x + ((size_t)b * TDIM + tid) * DDIM);
    float2* w01p = (float2*)(sbuf + W01_OFF);
    w01p[(size_t)b * TDIM + tid] =
        (tid == 0) ? make_float2(0.f, 0.f) : make_float2(v.x * inv_long, v.y);
    // full-t sums (include t=0)
    float sa = v.x, sb = v.y;
    #pragma unroll
    for (int off = 1; off < 64; off <<= 1) {
      sa += __shfl_xor(sa, off, 64);
      sb += __shfl_xor(sb, off, 64);
    }
    const int wave = tid >> 6, lane = tid & 63;
    if (lane == 0) { rsum[wave] = sa; rsum[8 + wave] = sb; }
    __syncthreads();
    if (tid == 0) {
      float Sa = 0.f, Sb = 0.f;
      #pragma unroll
      for (int w = 0; w < 8; ++w) { Sa += rsum[w]; Sb += rsum[8 + w]; }
      sbuf[W_OFF + b * 2 + 0] = Sa * inv_long;
      sbuf[W_OFF + b * 2 + 1] = Sb;
    }
  }
}

// Grid: (128, 8), 512 threads = 8 waves, zero in-loop barriers.
// Wave = (tq = wave>>1: 128-t quarter, hp = wave&1: 16-h slice).
// hh for this block's 128 gate-cols computed inline in the prologue
// (64 MACs/thread, 4 threads/col) — hidden under 8-wave startup, no
// standalone scattered-GEMV kernel. A-fragments load directly as bf16.
__global__ __launch_bounds__(512, 4) void fused_lstm(
    const float* __restrict__ h0, const float* __restrict__ c0,
    const float* __restrict__ Wih, const float* __restrict__ Whh,
    const float* __restrict__ bih, const float* __restrict__ bhh,
    float* __restrict__ sbuf)
{
  const int b    = blockIdx.x;
  const int hcq  = blockIdx.y;          // 0..7
  const int tid  = threadIdx.x;
  const int wave = tid >> 6;            // 0..7
  const int lane = tid & 63;
  const int col  = lane & 15;
  const int kg   = lane >> 4;           // 0..3
  const int hp   = wave & 1;
  const int tq   = wave >> 1;           // 0..3
  const int hc   = hcq * 2 + hp;        // 0..15
  const int h    = hc * 16 + col;

  __shared__ float2 ws01[TDIM];         // 4KB
  __shared__ float red[8 * 64];         // 2KB
  __shared__ float h0s[HDIM];           // 1KB
  __shared__ float hhsc[128];           // pre-scaled hh for this block's cols

  const float2* w01p = (const float2*)(sbuf + W01_OFF);
  const short* xbfs = (const short*)(sbuf + XBF_OFF);

  if (tid < HDIM) h0s[tid] = h0[b * HDIM + tid];
  ws01[tid] = w01p[(size_t)b * TDIM + tid];   // coalesced 4KB stage
  __syncthreads();

  // ---- inline hh for the block's 128 gate-cols: 4 threads/col, 64 MAC ----
  {
    const int col2 = tid >> 2;          // 0..127
    const int part = tid & 3;
    const int g2   = col2 >> 5;         // 0..3
    const int lh   = col2 & 31;
    const int colw = g2 * HDIM + hcq * 32 + lh;
    const float4* wr = (const float4*)(Whh + (size_t)colw * HDIM) + part * 16;
    const float4* hv = (const float4*)h0s + part * 16;
    float acc = 0.f;
    #pragma unroll 8
    for (int k = 0; k < 16; ++k) {
      float4 w = wr[k], h4 = hv[k];
      acc += w.x * h4.x + w.y * h4.y + w.z * h4.z + w.w * h4.w;
    }
    acc += __shfl_xor(acc, 1, 64);
    acc += __shfl_xor(acc, 2, 64);
    if (part == 0) {
      const float sc = (g2 == 2) ? 2.f * L2E : L2E;
      hhsc[col2] = (acc + bih[colw] + bhh[colw]) * sc;
    }
  }
  __syncthreads();

  float hhv[4];
  #pragma unroll
  for (int g = 0; g < 4; ++g) hhv[g] = hhsc[g * 32 + hp * 16 + col];
  const float cprev = c0[b * HDIM + h];

  // W_ih fragments (B operand), pre-scaled by log2e (2*log2e for gate 2)
  s16x8 wf[4][2];
  #pragma unroll
  for (int g = 0; g < 4; ++g) {
    const float sc = (g == 2) ? 2.f * L2E : L2E;
    const float4* wrow = (const float4*)(Wih + (size_t)(g * HDIM + h) * DDIM);
    #pragma unroll
    for (int ks = 0; ks < 2; ++ks)
      wf[g][ks] = pack_bf8s(wrow[kg * 2 + ks * 8], wrow[kg * 2 + ks * 8 + 1], sc);
  }

  // A rows: bf16 row stride 64 shorts; lane reads 16B at kg*8 (+32 for k+32)
  const int t0w = tq * 128;
  const short* xr = xbfs + ((size_t)b * TDIM + t0w + col) * DDIM + kg * 8;

  s16x8 A0a, A1a, A0b, A1b;
  #define LOADT(i, V0, V1) { const short* p = xr + (size_t)(i) * 16 * DDIM; \
      V0 = *(const s16x8*)p; V1 = *(const s16x8*)(p + 32); }

  float s0h = 0.f, s1h = 0.f, s0c = 0.f, s1c = 0.f;

  #define COMPUTE(i, V0, V1) {                                               \
    f32x4 acc[4];                                                            \
    _Pragma("unroll")                                                        \
    for (int g = 0; g < 4; ++g) {                                            \
      f32x4 zc = {hhv[g], hhv[g], hhv[g], hhv[g]};                           \
      zc = __builtin_amdgcn_mfma_f32_16x16x32_bf16(V0, wf[g][0], zc, 0,0,0); \
      zc = __builtin_amdgcn_mfma_f32_16x16x32_bf16(V1, wf[g][1], zc, 0,0,0); \
      acc[g] = zc;                                                           \
    }                                                                        \
    _Pragma("unroll")                                                        \
    for (int r = 0; r < 4; ++r) {                                            \
      float2 wv = ws01[t0w + (i) * 16 + kg * 4 + r];                         \
      float ig = rcpf(1.f + EXP2(-acc[0][r]));                               \
      float fg = rcpf(1.f + EXP2(-acc[1][r]));                               \
      float gg = fmaf(-2.f, rcpf(EXP2(acc[2][r]) + 1.f), 1.f);               \
      float og = rcpf(1.f + EXP2(-acc[3][r]));                               \
      float cc = fmaf(fg, cprev, ig * gg);                                   \
      float th = fmaf(-2.f, rcpf(EXP2(cc * (2.f * L2E)) + 1.f), 1.f);        \
      float hv = og * th;                                                    \
      s0h = fmaf(hv, wv.x, s0h); s1h = fmaf(hv, wv.y, s1h);                  \
      s0c = fmaf(cc, wv.x, s0c); s1c = fmaf(cc, wv.y, s1c);                  \
    } }

  LOADT(0, A0a, A1a);
  LOADT(1, A0b, A1b);
  COMPUTE(0, A0a, A1a); LOADT(2, A0a, A1a);
  COMPUTE(1, A0b, A1b); LOADT(3, A0b, A1b);
  COMPUTE(2, A0a, A1a); LOADT(4, A0a, A1a);
  COMPUTE(3, A0b, A1b); LOADT(5, A0b, A1b);
  COMPUTE(4, A0a, A1a); LOADT(6, A0a, A1a);
  COMPUTE(5, A0b, A1b); LOADT(7, A0b, A1b);
  COMPUTE(6, A0a, A1a);
  COMPUTE(7, A0b, A1b);

  // reduce over the 4 k-groups (lanes sharing col)
  s0h += __shfl_xor(s0h, 16, 64); s0h += __shfl_xor(s0h, 32, 64);
  s1h += __shfl_xor(s1h, 16, 64); s1h += __shfl_xor(s1h, 32, 64);
  s0c += __shfl_xor(s0c, 16, 64); s0c += __shfl_xor(s0c, 32, 64);
  s1c += __shfl_xor(s1c, 16, 64); s1c += __shfl_xor(s1c, 32, 64);

  if (kg == 0) {
    red[wave * 64 +  0 + col] = s0h;    // w01 already carries /long + t=0 mask
    red[wave * 64 + 16 + col] = s1h;
    red[wave * 64 + 32 + col] = s0c;
    red[wave * 64 + 48 + col] = s1c;
  }
  __syncthreads();

  if (tid < 128) {
    const int hp2 = tid >> 6;
    const int q   = (tid >> 4) & 3;
    const int c   = tid & 15;
    const int o   = q * 16 + c;
    float s = red[(0 + hp2) * 64 + o] + red[(2 + hp2) * 64 + o] +
              red[(4 + hp2) * 64 + o] + red[(6 + hp2) * 64 + o];
    const int h2 = (hcq * 2 + hp2) * 16 + c;
    sbuf[(size_t)q * BH + b * HDIM + h2] = s;
  }
}

// Grid: 128 blocks (b), 256 threads. Pure GEMV epilogue.
__global__ __launch_bounds__(256) void out_kernel(
    const float* __restrict__ f1w, const float* __restrict__ f1b,
    const float* __restrict__ f2w, const float* __restrict__ f2b,
    const float* __restrict__ sbuf, float* __restrict__ out)
{
  const int b = blockIdx.x, tid = threadIdx.x;
  __shared__ float s0h[256], s1h[256], s0c[256], s1c[256];

  s0h[tid] = sbuf[(size_t)0 * BH + b * HDIM + tid];
  s1h[tid] = sbuf[(size_t)1 * BH + b * HDIM + tid];
  s0c[tid] = sbuf[(size_t)2 * BH + b * HDIM + tid];
  s1c[tid] = sbuf[(size_t)3 * BH + b * HDIM + tid];
  __syncthreads();

  const float W0 = sbuf[W_OFF + b * 2 + 0];
  const float W1 = sbuf[W_OFF + b * 2 + 1];

  float rh, rc;
  if (tid < 128) {                       // "first": f1_w with w0-weighted sums
    const float4* wr = (const float4*)(f1w + (size_t)tid * HDIM);
    float ah = 0.f, ac = 0.f;
    #pragma unroll 8
    for (int k = 0; k < HDIM / 4; ++k) {
      float4 w = wr[k];
      ah += w.x * s0h[4*k] + w.y * s0h[4*k+1] + w.z * s0h[4*k+2] + w.w * s0h[4*k+3];
      ac += w.x * s0c[4*k] + w.y * s0c[4*k+1] + w.z * s0c[4*k+2] + w.w * s0c[4*k+3];
    }
    const float bb = f1b[tid];
    rh = ah + bb * W0;
    rc = ac + bb * W0;
  } else {                               // "second": f2_w with w1-weighted sums
    const int k0 = tid - 128;
    const float4* wr = (const float4*)(f2w + (size_t)k0 * HDIM);
    float ah = 0.f, ac = 0.f;
    #pragma unroll 8
    for (int k = 0; k < HDIM / 4; ++k) {
      float4 w = wr[k];
      ah += w.x * s1h[4*k] + w.y * s1h[4*k+1] + w.z * s1h[4*k+2] + w.w * s1h[4*k+3];
      ac += w.x * s1c[4*k] + w.y * s1c[4*k+1] + w.z * s1c[4*k+2] + w.w * s1c[4*k+3];
    }
    const float bb = f2b[k0];
    rh = ah + bb * W1;
    rc = ac + bb * W1;
  }
  out[b * HDIM + tid] = rh;                      // agg(h_all) -> (1,B,256)
  out[BDIM * HDIM + b * HDIM + tid] = rc;        // agg(c_all)
}

extern "C" void kernel_launch(void* const* d_in, const int* in_sizes, int n_in,
                              void* d_out, int out_size, void* d_ws, size_t ws_size,
                              hipStream_t stream) {
  const float* x   = (const float*)d_in[0];
  const float* h0  = (const float*)d_in[1];
  const float* c0  = (const float*)d_in[2];
  const float* Wih = (const float*)d_in[3];
  const float* Whh = (const float*)d_in[4];
  const float* bih = (const float*)d_in[5];
  const float* bhh = (const float*)d_in[6];
  const float* f1w = (const float*)d_in[7];
  const float* f1b = (const float*)d_in[8];
  const float* f2w = (const float*)d_in[9];
  const float* f2b = (const float*)d_in[10];
  const int*  longp = (const int*)d_in[11];
  float* out  = (float*)d_out;
  float* sbuf = (float*)d_ws;   // planes+W+w01 (~1MB) + xbf16 (8.4MB)

  pre_kernel<<<NPRE, 512, 0, stream>>>(x, longp, sbuf);
  dim3 g1(BDIM, 8);
  fused_lstm<<<g1, 512, 0, stream>>>(h0, c0, Wih, Whh, bih, bhh, sbuf);
  out_kernel<<<BDIM, 256, 0, stream>>>(f1w, f1b, f2w, f2b, sbuf, out);
}